// Round 1
// baseline (10010.841 us; speedup 1.0000x reference)
//
#include <hip/hip_runtime.h>
#include <hip/hip_bf16.h>

typedef float f32;
typedef __hip_bfloat16 bf16;

#define T_LEN 128
#define B_SZ  64
#define E_DIM 512
#define U_DIM 1024
#define G3    3072

// workspace layout (bytes)
#define WS_UT 0u                    // f32 [2][3072][1024]   = 25165824 B
#define WS_H  25165824u             // f32 [2][2][1024][64]  = 1048576 B (double-buffered h, [buf][dir][u][b])
#define WS_XG 26214400u             // bf16 [2][128][3072][64] = 100663296 B  ([dir][step][col][b])

// ---------------- U transpose: UT[d][c][k] = U_d[k][c] ----------------
__global__ __launch_bounds__(256) void transpose_u(
    const f32* __restrict__ Uf, const f32* __restrict__ Ub, f32* __restrict__ UT)
{
  __shared__ f32 tile[32][33];
  const int d = blockIdx.z;
  const f32* Uw = d ? Ub : Uf;
  const int c0 = blockIdx.x * 32;
  const int k0 = blockIdx.y * 32;
  const int tx = threadIdx.x & 31;
  const int ty = threadIdx.x >> 5;
#pragma unroll
  for (int i = 0; i < 4; i++) {
    int k = ty + i * 8;
    tile[k][tx] = Uw[(size_t)(k0 + k) * G3 + c0 + tx];
  }
  __syncthreads();
#pragma unroll
  for (int i = 0; i < 4; i++) {
    int c = ty + i * 8;
    UT[((size_t)d * G3 + c0 + c) * U_DIM + k0 + tx] = tile[tx][c];
  }
}

// ---------------- input projection: XG[d][s][col][b] = emb[tok(d,s,b)] @ W_d + bi_d ----------------
// M = 16384 rows ((d,s,b) flattened, d-major), N = 3072, K = 512. f32 tiled GEMM 128x128, 8x8 micro.
__global__ __launch_bounds__(256) void xg_gemm(
    const int* __restrict__ tokens, const f32* __restrict__ emb,
    const f32* __restrict__ Wf, const f32* __restrict__ bif,
    const f32* __restrict__ Wb, const f32* __restrict__ bib,
    bf16* __restrict__ XG)
{
  __shared__ f32 As[8][128];   // [k][m]
  __shared__ f32 Bs[8][128];   // [k][n]
  __shared__ int tok_s[128];

  const int tid = threadIdx.x;
  const int n0 = blockIdx.x * 128;
  const int m0 = blockIdx.y * 128;
  const int dir = (m0 >= T_LEN * B_SZ) ? 1 : 0;
  const f32* W  = dir ? Wb : Wf;
  const f32* bi = dir ? bib : bif;

  if (tid < 128) {
    int mm = m0 + tid - dir * (T_LEN * B_SZ);
    int s = mm >> 6, b = mm & 63;
    // fwd scan step s consumes reversed-token column 127-s; bwd scan step s consumes column s
    int t_orig = dir ? s : (T_LEN - 1 - s);
    tok_s[tid] = tokens[b * T_LEN + t_orig];
  }
  __syncthreads();

  const int lr = tid >> 1;          // A-load row 0..127
  const int lh = (tid & 1) * 4;     // e offset 0/4
  const int bk = tid >> 5;          // B-load k 0..7
  const int bn = (tid & 31) * 4;    // B-load col
  const f32* arow = emb + (size_t)tok_s[lr] * E_DIM + lh;
  const f32* brow = W + (size_t)bk * G3 + n0 + bn;

  const int tm = tid >> 4;          // 0..15
  const int tn = tid & 15;          // 0..15

  f32 acc[8][8];
#pragma unroll
  for (int i = 0; i < 8; i++)
#pragma unroll
    for (int j = 0; j < 8; j++) acc[i][j] = 0.f;

  for (int k0 = 0; k0 < E_DIM; k0 += 8) {
    float4 av = *(const float4*)(arow + k0);
    float4 bv = *(const float4*)(brow + (size_t)k0 * G3);
    __syncthreads();
    As[lh + 0][lr] = av.x;
    As[lh + 1][lr] = av.y;
    As[lh + 2][lr] = av.z;
    As[lh + 3][lr] = av.w;
    *(float4*)&Bs[bk][bn] = bv;
    __syncthreads();
#pragma unroll
    for (int kk = 0; kk < 8; kk++) {
      float4 a0 = *(float4*)&As[kk][tm * 4];
      float4 a1 = *(float4*)&As[kk][64 + tm * 4];
      float4 b0 = *(float4*)&Bs[kk][tn * 4];
      float4 b1 = *(float4*)&Bs[kk][64 + tn * 4];
      f32 am[8] = {a0.x,a0.y,a0.z,a0.w,a1.x,a1.y,a1.z,a1.w};
      f32 bb[8] = {b0.x,b0.y,b0.z,b0.w,b1.x,b1.y,b1.z,b1.w};
#pragma unroll
      for (int i = 0; i < 8; i++)
#pragma unroll
        for (int j = 0; j < 8; j++)
          acc[i][j] += am[i] * bb[j];
    }
  }

  f32 biv[8];
#pragma unroll
  for (int j = 0; j < 8; j++) {
    int nloc = tn * 4 + (j & 3) + (j >> 2) * 64;
    biv[j] = bi[n0 + nloc];
  }
#pragma unroll
  for (int i = 0; i < 8; i++) {
    int mloc = tm * 4 + (i & 3) + (i >> 2) * 64;
    int mm = m0 + mloc - dir * (T_LEN * B_SZ);
    int s = mm >> 6, b = mm & 63;
    size_t rowbase = ((size_t)(dir * T_LEN + s) * G3) * B_SZ + b;
#pragma unroll
    for (int j = 0; j < 8; j++) {
      int nloc = tn * 4 + (j & 3) + (j >> 2) * 64;
      XG[rowbase + (size_t)(n0 + nloc) * B_SZ] = __float2bfloat16(acc[i][j] + biv[j]);
    }
  }
}

// ---------------- one recurrence step (both directions), launched 128x ----------------
// 512 blocks x 256 threads. block -> (dir, 4 hidden units); thread -> (b = tid&63, u = u0 + (tid>>6)).
// Each thread computes hz,hr,hh dot-products over K=1024 (H staged in LDS), then the gate math.
__global__ __launch_bounds__(256) void gru_step(
    const f32* __restrict__ UT,       // [2][3072][1024]
    const bf16* __restrict__ XG,      // [2][128][3072][64]
    const f32* __restrict__ bhf, const f32* __restrict__ bhb,
    f32* __restrict__ H,              // [2][2][1024][64]
    f32* __restrict__ out,            // d_out: [64][128][1024] f32 + hidden [64][2048]
    int s)
{
  const int bx   = blockIdx.x;
  const int dir  = bx >> 8;
  const int ublk = bx & 255;
  const int tid  = threadIdx.x;
  const int b    = tid & 63;
  const int ug   = tid >> 6;
  const int u    = ublk * 4 + ug;
  const int cur  = s & 1, nxt = cur ^ 1;

  __shared__ f32 Hs[128][64];

  const f32* hcur = H + ((size_t)cur * 2 + dir) * (U_DIM * B_SZ);
  f32*       hnxt = H + ((size_t)nxt * 2 + dir) * (U_DIM * B_SZ);

  const int us = __builtin_amdgcn_readfirstlane(u);   // wave-uniform
  const f32* up0 = UT + ((size_t)dir * G3 +        us) * U_DIM;
  const f32* up1 = UT + ((size_t)dir * G3 + 1024 + us) * U_DIM;
  const f32* up2 = UT + ((size_t)dir * G3 + 2048 + us) * U_DIM;

  f32 acc0 = 0.f, acc1 = 0.f, acc2 = 0.f;

  for (int k0 = 0; k0 < U_DIM; k0 += 128) {
    __syncthreads();
    {
      int kk = tid >> 4;            // 0..15
      int b4 = (tid & 15) * 4;
#pragma unroll
      for (int r = 0; r < 8; r++) {
        float4 v = *(const float4*)(hcur + (size_t)(k0 + kk + r * 16) * B_SZ + b4);
        *(float4*)&Hs[kk + r * 16][b4] = v;
      }
    }
    __syncthreads();
#pragma unroll 8
    for (int k = 0; k < 128; k++) {
      f32 h = Hs[k][b];
      acc0 += h * up0[k0 + k];
      acc1 += h * up1[k0 + k];
      acc2 += h * up2[k0 + k];
    }
  }

  const f32* bh = dir ? bhb : bhf;
  f32 hz = acc0 + bh[u];
  f32 hr = acc1 + bh[1024 + u];
  f32 hh = acc2 + bh[2048 + u];

  size_t xgbase = ((size_t)(dir * T_LEN + s) * G3) * B_SZ + b;
  f32 xz = __bfloat162float(XG[xgbase + (size_t)(u)        * B_SZ]);
  f32 xr = __bfloat162float(XG[xgbase + (size_t)(1024 + u) * B_SZ]);
  f32 xh = __bfloat162float(XG[xgbase + (size_t)(2048 + u) * B_SZ]);

  f32 hold = hcur[(size_t)u * B_SZ + b];
  f32 z  = 1.f / (1.f + expf(-(xz + hz)));
  f32 r  = 1.f / (1.f + expf(-(xr + hr)));
  f32 hc = tanhf(xh + r * hh);
  f32 hnew = z * hold + (1.f - z) * hc;

  hnxt[(size_t)u * B_SZ + b] = hnew;

  // outputs[b][t][u] = fwd_scan[t] + bwd_scan[127-t]; first toucher stores, second adds.
  int t = dir ? (T_LEN - 1 - s) : s;
  size_t oidx = ((size_t)b * T_LEN + t) * U_DIM + u;
  if (s < 64) out[oidx] = hnew;
  else        out[oidx] += hnew;

  if (s == T_LEN - 1) {
    // hidden = concat(h_f, h_b): d_out offset B*T*U
    out[(size_t)B_SZ * T_LEN * U_DIM + (size_t)b * 2048 + dir * 1024 + u] = hnew;
  }
}

extern "C" void kernel_launch(void* const* d_in, const int* in_sizes, int n_in,
                              void* d_out, int out_size, void* d_ws, size_t ws_size,
                              hipStream_t stream) {
  (void)in_sizes; (void)n_in; (void)out_size; (void)ws_size;
  const int* tokens = (const int*)d_in[0];
  const f32* emb = (const f32*)d_in[1];
  const f32* Wf  = (const f32*)d_in[2];
  const f32* Uf  = (const f32*)d_in[3];
  const f32* bif = (const f32*)d_in[4];
  const f32* bhf = (const f32*)d_in[5];
  const f32* Wb  = (const f32*)d_in[6];
  const f32* Ub  = (const f32*)d_in[7];
  const f32* bib = (const f32*)d_in[8];
  const f32* bhb = (const f32*)d_in[9];

  char* ws = (char*)d_ws;
  f32*  UT = (f32*)(ws + WS_UT);
  f32*  H  = (f32*)(ws + WS_H);
  bf16* XG = (bf16*)(ws + WS_XG);
  f32*  out = (f32*)d_out;

  hipMemsetAsync(H, 0, (size_t)2 * 2 * U_DIM * B_SZ * sizeof(f32), stream);
  transpose_u<<<dim3(96, 32, 2), 256, 0, stream>>>(Uf, Ub, UT);
  xg_gemm<<<dim3(24, 128), 256, 0, stream>>>(tokens, emb, Wf, bif, Wb, bib, XG);
  for (int s = 0; s < T_LEN; s++)
    gru_step<<<512, 256, 0, stream>>>(UT, XG, bhf, bhb, H, out, s);
}

// Round 2
// 2171.933 us; speedup vs baseline: 4.6092x; 4.6092x over previous
//
#include <hip/hip_runtime.h>
#include <hip/hip_bf16.h>

typedef float f32;
typedef __hip_bfloat16 bf16;
typedef unsigned int u32;
typedef unsigned short u16;

#define T_LEN 128
#define B_SZ  64
#define E_DIM 512
#define U_DIM 1024
#define G3    3072
#define BTU   (B_SZ * T_LEN * U_DIM)

typedef __attribute__((ext_vector_type(8))) __bf16 bf16x8;
typedef __attribute__((ext_vector_type(8))) u16  us8;
typedef __attribute__((ext_vector_type(4))) f32  f32x4;

union F8 { us8 u; bf16x8 b; };

// workspace layout (bytes) — total 126,877,696 (same as round-1, known to fit)
#define WS_USW 0u            // bf16 bits [256 blk][2 plane][24 row][1024 k] swizzled = 25165824 B
#define WS_HQ  25165824u     // u32 [2 buf][2 dir][1024 u][64 b] packed (hi lo16 | lo hi16) = 1048576 B
#define WS_XG  26214400u     // bf16 [2][128][3072][64] = 100663296 B

__device__ __forceinline__ u32 f32_to_bf16_rne(f32 x) {
  u32 b = __float_as_uint(x);
  return (b + 0x7fffu + ((b >> 16) & 1u)) >> 16;
}

// ---------------- U transpose + hi/lo split + per-block swizzled image ----------------
// USW[blk][plane][row][k], blk = dir*128 + (u>>3), row = gate*8 + (u&7), 24 rows/blk.
// Within each 2048-B row, 16-B slot index is XOR-swizzled by (row&7) for conflict-free LDS reads.
__global__ __launch_bounds__(256) void transpose_split(
    const f32* __restrict__ Uf, const f32* __restrict__ Ub, u16* __restrict__ USW)
{
  __shared__ f32 tile[32][33];
  const int d = blockIdx.z;
  const f32* Uw = d ? Ub : Uf;
  const int c0 = blockIdx.x * 32;
  const int k0 = blockIdx.y * 32;
  const int tx = threadIdx.x & 31;
  const int ty = threadIdx.x >> 5;
#pragma unroll
  for (int i = 0; i < 4; i++) {
    int kl = ty + i * 8;
    tile[kl][tx] = Uw[(size_t)(k0 + kl) * G3 + c0 + tx];
  }
  __syncthreads();
#pragma unroll
  for (int i = 0; i < 4; i++) {
    int cl = ty + i * 8;
    int c  = c0 + cl;
    f32 val = tile[tx][cl];          // = U_d[k0+tx][c]
    int g = c >> 10, u = c & 1023;
    int blk = d * 128 + (u >> 3);
    int r   = g * 8 + (u & 7);       // 0..23
    u32 hib = f32_to_bf16_rne(val);
    f32 rem = val - __uint_as_float(hib << 16);
    u32 lob = f32_to_bf16_rne(rem);
    int k = k0 + tx;
    int slot = (k >> 3) ^ (r & 7);   // swizzled 16B slot
    size_t base = ((size_t)blk * 2) * (24 * 1024);
    size_t off  = (size_t)r * 1024 + slot * 8 + (k & 7);
    USW[base + off] = (u16)hib;
    USW[base + (size_t)24 * 1024 + off] = (u16)lob;
  }
}

// ---------------- input projection (unchanged from round 1): XG[d][s][col][b] ----------------
__global__ __launch_bounds__(256) void xg_gemm(
    const int* __restrict__ tokens, const f32* __restrict__ emb,
    const f32* __restrict__ Wf, const f32* __restrict__ bif,
    const f32* __restrict__ Wb, const f32* __restrict__ bib,
    bf16* __restrict__ XG)
{
  __shared__ f32 As[8][128];
  __shared__ f32 Bs[8][128];
  __shared__ int tok_s[128];

  const int tid = threadIdx.x;
  const int n0 = blockIdx.x * 128;
  const int m0 = blockIdx.y * 128;
  const int dir = (m0 >= T_LEN * B_SZ) ? 1 : 0;
  const f32* W  = dir ? Wb : Wf;
  const f32* bi = dir ? bib : bif;

  if (tid < 128) {
    int mm = m0 + tid - dir * (T_LEN * B_SZ);
    int s = mm >> 6, b = mm & 63;
    int t_orig = dir ? s : (T_LEN - 1 - s);
    tok_s[tid] = tokens[b * T_LEN + t_orig];
  }
  __syncthreads();

  const int lr = tid >> 1;
  const int lh = (tid & 1) * 4;
  const int bk = tid >> 5;
  const int bn = (tid & 31) * 4;
  const f32* arow = emb + (size_t)tok_s[lr] * E_DIM + lh;
  const f32* brow = W + (size_t)bk * G3 + n0 + bn;

  const int tm = tid >> 4;
  const int tn = tid & 15;

  f32 acc[8][8];
#pragma unroll
  for (int i = 0; i < 8; i++)
#pragma unroll
    for (int j = 0; j < 8; j++) acc[i][j] = 0.f;

  for (int k0 = 0; k0 < E_DIM; k0 += 8) {
    float4 av = *(const float4*)(arow + k0);
    float4 bv = *(const float4*)(brow + (size_t)k0 * G3);
    __syncthreads();
    As[lh + 0][lr] = av.x;
    As[lh + 1][lr] = av.y;
    As[lh + 2][lr] = av.z;
    As[lh + 3][lr] = av.w;
    *(float4*)&Bs[bk][bn] = bv;
    __syncthreads();
#pragma unroll
    for (int kk = 0; kk < 8; kk++) {
      float4 a0 = *(float4*)&As[kk][tm * 4];
      float4 a1 = *(float4*)&As[kk][64 + tm * 4];
      float4 b0 = *(float4*)&Bs[kk][tn * 4];
      float4 b1 = *(float4*)&Bs[kk][64 + tn * 4];
      f32 am[8] = {a0.x,a0.y,a0.z,a0.w,a1.x,a1.y,a1.z,a1.w};
      f32 bb[8] = {b0.x,b0.y,b0.z,b0.w,b1.x,b1.y,b1.z,b1.w};
#pragma unroll
      for (int i = 0; i < 8; i++)
#pragma unroll
        for (int j = 0; j < 8; j++)
          acc[i][j] += am[i] * bb[j];
    }
  }

  f32 biv[8];
#pragma unroll
  for (int j = 0; j < 8; j++) {
    int nloc = tn * 4 + (j & 3) + (j >> 2) * 64;
    biv[j] = bi[n0 + nloc];
  }
#pragma unroll
  for (int i = 0; i < 8; i++) {
    int mloc = tm * 4 + (i & 3) + (i >> 2) * 64;
    int mm = m0 + mloc - dir * (T_LEN * B_SZ);
    int s = mm >> 6, b = mm & 63;
    size_t rowbase = ((size_t)(dir * T_LEN + s) * G3) * B_SZ + b;
#pragma unroll
    for (int j = 0; j < 8; j++) {
      int nloc = tn * 4 + (j & 3) + (j >> 2) * 64;
      XG[rowbase + (size_t)(n0 + nloc) * B_SZ] = __float2bfloat16(acc[i][j] + biv[j]);
    }
  }
}

// ---------------- one recurrence step, MFMA + hi/lo split, launched 128x ----------------
// 256 blocks (dir x 128 u-slices of 8) x 512 threads (8 waves: 4 batch-tiles x 2 k-halves).
// P[row][b] = U_slice @ h : rows 0-7=z, 8-15=r, 16-23=hcand (M-tiles 0..15 / 16..31, pad discarded).
__global__ __launch_bounds__(512) void gru_step_mfma(
    const u16* __restrict__ USW,
    u32* __restrict__ Hq,            // [2 buf][2 dir][1024][64] packed bf16 pairs
    const u16* __restrict__ XG,      // bf16 bits [2][128][3072][64]
    const f32* __restrict__ bhf, const f32* __restrict__ bhb,
    f32* __restrict__ out, int s)
{
  extern __shared__ u16 Us[];        // [2][24][1024] swizzled = 98304 B (aliased as red later)
  const int blk = blockIdx.x;
  const int dir = blk >> 7;
  const int su  = (blk & 127) * 8;
  const int tid = threadIdx.x;
  const int lane = tid & 63;
  const int w  = tid >> 6;
  const int nw = w & 3, kw = w >> 2;

  // stage per-block U image (linear copy; swizzle already baked into global layout)
  {
    const us8* src = (const us8*)(USW + (size_t)blk * (2 * 24 * 1024));
    us8* dst = (us8*)Us;
    for (int i = tid; i < (2 * 24 * 1024) / 8; i += 512) dst[i] = src[i];
  }

  const u32* Hin  = Hq + (size_t)((s & 1) * 2 + dir) * (U_DIM * B_SZ);
  u32*       Hout = Hq + (size_t)(((s + 1) & 1) * 2 + dir) * (U_DIM * B_SZ);

  const int bb = nw * 16 + (lane & 15);
  const int ko = (lane >> 4) * 8;
  const int r0 = lane & 15;
  const int r1t = 16 + (lane & 15);
  const int r1 = r1t > 23 ? 23 : r1t;   // clamp: rows 24..31 are discarded anyway

  const int rb_h0 = (0 * 24 + r0) * 2048;
  const int rb_l0 = (1 * 24 + r0) * 2048;
  const int rb_h1 = (0 * 24 + r1) * 2048;
  const int rb_l1 = (1 * 24 + r1) * 2048;
  const int sw0 = r0 & 7, sw1 = r1 & 7;

  __syncthreads();

  f32x4 acc0 = {0.f, 0.f, 0.f, 0.f};
  f32x4 acc1 = {0.f, 0.f, 0.f, 0.f};

  for (int ks = 0; ks < 16; ks++) {
    const int kb = kw * 512 + ks * 32;
    const int slot = (kb >> 3) + (lane >> 4);
    F8 ah0, al0, ah1, al1;
    ah0.u = *(const us8*)((const char*)Us + rb_h0 + ((slot ^ sw0) << 4));
    al0.u = *(const us8*)((const char*)Us + rb_l0 + ((slot ^ sw0) << 4));
    ah1.u = *(const us8*)((const char*)Us + rb_h1 + ((slot ^ sw1) << 4));
    al1.u = *(const us8*)((const char*)Us + rb_l1 + ((slot ^ sw1) << 4));

    const int kbase = kb + ko;
    u32 wd[8];
#pragma unroll
    for (int e = 0; e < 8; e++) wd[e] = Hin[(size_t)(kbase + e) * B_SZ + bb];
    F8 bh_hi, bh_lo;
#pragma unroll
    for (int e = 0; e < 8; e++) {
      bh_hi.u[e] = (u16)(wd[e] & 0xffffu);
      bh_lo.u[e] = (u16)(wd[e] >> 16);
    }
    // (Uhi+Ulo)(hhi+hlo) ~= Uhi*hhi + Uhi*hlo + Ulo*hhi
    acc0 = __builtin_amdgcn_mfma_f32_16x16x32_bf16(ah0.b, bh_hi.b, acc0, 0, 0, 0);
    acc0 = __builtin_amdgcn_mfma_f32_16x16x32_bf16(ah0.b, bh_lo.b, acc0, 0, 0, 0);
    acc0 = __builtin_amdgcn_mfma_f32_16x16x32_bf16(al0.b, bh_hi.b, acc0, 0, 0, 0);
    acc1 = __builtin_amdgcn_mfma_f32_16x16x32_bf16(ah1.b, bh_hi.b, acc1, 0, 0, 0);
    acc1 = __builtin_amdgcn_mfma_f32_16x16x32_bf16(ah1.b, bh_lo.b, acc1, 0, 0, 0);
    acc1 = __builtin_amdgcn_mfma_f32_16x16x32_bf16(al1.b, bh_hi.b, acc1, 0, 0, 0);
  }

  // k-half reduction through LDS (reuse staging area — all reads of Us are done)
  __syncthreads();
  f32* red = (f32*)Us;               // [4][64][8]
  if (kw == 1) {
    f32* p = red + (size_t)(nw * 64 + lane) * 8;
    *(f32x4*)p = acc0;
    *(f32x4*)(p + 4) = acc1;
  }
  __syncthreads();
  if (kw == 0) {
    const f32* p = red + (size_t)(nw * 64 + lane) * 8;
    f32x4 o0 = *(const f32x4*)p;
    f32x4 o1 = *(const f32x4*)(p + 4);
#pragma unroll
    for (int i = 0; i < 4; i++) { acc0[i] += o0[i]; acc1[i] += o1[i]; }

    const f32* bh = dir ? bhb : bhf;
    f32 racc[4];
#pragma unroll
    for (int j = 0; j < 4; j++) racc[j] = __shfl_xor(acc0[j], 32);   // r-gate rows (8..15)

    if (lane < 32) {
      const size_t xgb = ((size_t)(dir * T_LEN + s) * G3) * B_SZ + bb;
      const int t = dir ? (T_LEN - 1 - s) : s;
#pragma unroll
      for (int j = 0; j < 4; j++) {
        const int ul = (lane >> 4) * 4 + j;   // 0..7
        const int u  = su + ul;
        f32 hz = acc0[j] + bh[u];
        f32 hr = racc[j] + bh[1024 + u];
        f32 hh = acc1[j] + bh[2048 + u];
        f32 xz = __uint_as_float((u32)XG[xgb + (size_t)u * B_SZ] << 16);
        f32 xr = __uint_as_float((u32)XG[xgb + (size_t)(1024 + u) * B_SZ] << 16);
        f32 xh = __uint_as_float((u32)XG[xgb + (size_t)(2048 + u) * B_SZ] << 16);

        u32 hw = Hin[(size_t)u * B_SZ + bb];
        f32 hold = __uint_as_float(hw << 16) + __uint_as_float(hw & 0xffff0000u);

        f32 z  = 1.f / (1.f + expf(-(xz + hz)));
        f32 r  = 1.f / (1.f + expf(-(xr + hr)));
        f32 hc = tanhf(xh + r * hh);
        f32 hnew = z * hold + (1.f - z) * hc;

        u32 hib = f32_to_bf16_rne(hnew);
        f32 rem = hnew - __uint_as_float(hib << 16);
        u32 lob = f32_to_bf16_rne(rem);
        Hout[(size_t)u * B_SZ + bb] = hib | (lob << 16);

        size_t oidx = ((size_t)bb * T_LEN + t) * U_DIM + u;
        if (s < 64) out[oidx] = hnew;
        else        out[oidx] += hnew;

        if (s == T_LEN - 1)
          out[(size_t)BTU + (size_t)bb * 2048 + dir * 1024 + u] = hnew;
      }
    }
  }
}

extern "C" void kernel_launch(void* const* d_in, const int* in_sizes, int n_in,
                              void* d_out, int out_size, void* d_ws, size_t ws_size,
                              hipStream_t stream) {
  (void)in_sizes; (void)n_in; (void)out_size; (void)ws_size;
  const int* tokens = (const int*)d_in[0];
  const f32* emb = (const f32*)d_in[1];
  const f32* Wf  = (const f32*)d_in[2];
  const f32* Uf  = (const f32*)d_in[3];
  const f32* bif = (const f32*)d_in[4];
  const f32* bhf = (const f32*)d_in[5];
  const f32* Wb  = (const f32*)d_in[6];
  const f32* Ub  = (const f32*)d_in[7];
  const f32* bib = (const f32*)d_in[8];
  const f32* bhb = (const f32*)d_in[9];

  char* ws = (char*)d_ws;
  u16*  USW = (u16*)(ws + WS_USW);
  u32*  Hq  = (u32*)(ws + WS_HQ);
  bf16* XG  = (bf16*)(ws + WS_XG);
  f32*  out = (f32*)d_out;

  hipMemsetAsync(Hq, 0, (size_t)2 * 2 * U_DIM * B_SZ * sizeof(u32), stream);
  transpose_split<<<dim3(96, 32, 2), 256, 0, stream>>>(Uf, Ub, USW);
  xg_gemm<<<dim3(24, 128), 256, 0, stream>>>(tokens, emb, Wf, bif, Wb, bib, XG);

  hipFuncSetAttribute((const void*)gru_step_mfma,
                      hipFuncAttributeMaxDynamicSharedMemorySize, 98304);
  for (int s = 0; s < T_LEN; s++)
    gru_step_mfma<<<256, 512, 98304, stream>>>(USW, Hq, (const u16*)XG, bhf, bhb, out, s);
}